// Round 1
// baseline (347.151 us; speedup 1.0000x reference)
//
#include <hip/hip_runtime.h>

#define NN 50000
#define NE 800000
#define KIN 256
#define DOUT 128
#define NEG_SLOPE 0.2f
#define ALPHA 0.5f

typedef __attribute__((ext_vector_type(8))) short bf16x8;
typedef __attribute__((ext_vector_type(4))) float f32x4;

__device__ __forceinline__ unsigned short f2b(float v) {
  unsigned int u = __float_as_uint(v);
  return (unsigned short)((u + 0x7fffu + ((u >> 16) & 1u)) >> 16);
}
__device__ __forceinline__ float b2f(unsigned short h) {
  return __uint_as_float(((unsigned int)h) << 16);
}

// ---- split fc_w into bf16 hi/lo, fragment-friendly layout:
// idx = ((kt*128 + c)*4 + g)*8 + j  for k = kt*32 + g*8 + j
__global__ void prep_b(const float* __restrict__ fc_w, unsigned short* __restrict__ b_hi,
                       unsigned short* __restrict__ b_lo) {
  int t = blockIdx.x * 256 + threadIdx.x;
  if (t >= KIN * DOUT) return;
  int k = t >> 7, c = t & 127;
  float v = fc_w[t];
  unsigned short h = f2b(v);
  unsigned short l = f2b(v - b2f(h));
  int kt = k >> 5, kl = k & 31;
  int g = kl >> 3, j = kl & 7;
  int idx = ((kt * 128 + c) * 4 + g) * 8 + j;
  b_hi[idx] = h;
  b_lo[idx] = l;
}

// ---- ft = feat @ fc_w via split-bf16 MFMA; fused el/er epilogue
__global__ __launch_bounds__(256) void gemm_ft(
    const float* __restrict__ feat, const unsigned short* __restrict__ b_hi,
    const unsigned short* __restrict__ b_lo, const float* __restrict__ attn_l,
    const float* __restrict__ attn_r, float* __restrict__ ft,
    float* __restrict__ el, float* __restrict__ er) {
  __shared__ unsigned short sA_hi[64][264];  // +8 pad: row stride 528B, balanced banks
  __shared__ unsigned short sA_lo[64][264];
  const int tid = threadIdx.x;
  const int row0 = blockIdx.x * 64;

#pragma unroll
  for (int i = 0; i < 16; ++i) {
    int f = tid + i * 256;
    int r = f >> 6;
    int c = (f & 63) * 4;
    int gr = row0 + r;
    float4 v = make_float4(0.f, 0.f, 0.f, 0.f);
    if (gr < NN) v = *(const float4*)(feat + (size_t)gr * KIN + c);
    unsigned short h0 = f2b(v.x), h1 = f2b(v.y), h2 = f2b(v.z), h3 = f2b(v.w);
    unsigned short l0 = f2b(v.x - b2f(h0)), l1 = f2b(v.y - b2f(h1));
    unsigned short l2 = f2b(v.z - b2f(h2)), l3 = f2b(v.w - b2f(h3));
    ushort4 hh; hh.x = h0; hh.y = h1; hh.z = h2; hh.w = h3;
    ushort4 ll; ll.x = l0; ll.y = l1; ll.z = l2; ll.w = l3;
    *(ushort4*)&sA_hi[r][c] = hh;
    *(ushort4*)&sA_lo[r][c] = ll;
  }
  __syncthreads();

  const int lane = tid & 63;
  const int wv = tid >> 6;
  const int rbase = wv * 16;      // wave's 16 rows within the 64-row tile
  const int cl = lane & 15;       // A-row / B-col within fragment
  const int g = lane >> 4;        // k-group
  const int frow = rbase + cl;
  const int boff0 = cl * 32 + g * 8;

  f32x4 acc[8];
#pragma unroll
  for (int ct = 0; ct < 8; ++ct) acc[ct] = (f32x4){0.f, 0.f, 0.f, 0.f};

#pragma unroll
  for (int kt = 0; kt < 8; ++kt) {
    bf16x8 ah = *(const bf16x8*)&sA_hi[frow][kt * 32 + g * 8];
    bf16x8 alo = *(const bf16x8*)&sA_lo[frow][kt * 32 + g * 8];
    const unsigned short* bh = b_hi + kt * 4096 + boff0;
    const unsigned short* bl = b_lo + kt * 4096 + boff0;
#pragma unroll
    for (int ct = 0; ct < 8; ++ct) {
      bf16x8 bhv = *(const bf16x8*)(bh + ct * 512);
      bf16x8 blv = *(const bf16x8*)(bl + ct * 512);
      acc[ct] = __builtin_amdgcn_mfma_f32_16x16x32_bf16(ah, bhv, acc[ct], 0, 0, 0);
      acc[ct] = __builtin_amdgcn_mfma_f32_16x16x32_bf16(alo, bhv, acc[ct], 0, 0, 0);
      acc[ct] = __builtin_amdgcn_mfma_f32_16x16x32_bf16(ah, blv, acc[ct], 0, 0, 0);
    }
  }

  // epilogue: C layout col=lane&15, row=(lane>>4)*4+q
  float pl[4] = {0, 0, 0, 0}, pr[4] = {0, 0, 0, 0};
  const int r0 = row0 + rbase + g * 4;
#pragma unroll
  for (int ct = 0; ct < 8; ++ct) {
    int col = ct * 16 + cl;
    float av = attn_l[col];
    float bv = attn_r[col];
#pragma unroll
    for (int q = 0; q < 4; ++q) {
      float v = acc[ct][q];
      int r = r0 + q;
      if (r < NN) ft[(size_t)r * DOUT + col] = v;
      pl[q] = fmaf(v, av, pl[q]);
      pr[q] = fmaf(v, bv, pr[q]);
    }
  }
#pragma unroll
  for (int q = 0; q < 4; ++q) {
    float a = pl[q], b = pr[q];
#pragma unroll
    for (int d = 1; d < 16; d <<= 1) {
      a += __shfl_xor(a, d);
      b += __shfl_xor(b, d);
    }
    if (cl == 0) {
      int r = r0 + q;
      if (r < NN) { el[r] = a; er[r] = b; }
    }
  }
}

// ---- CSR build
__global__ void hist_kernel(const int* __restrict__ dst, int* __restrict__ deg) {
  int e = blockIdx.x * 256 + threadIdx.x;
  if (e < NE) atomicAdd(&deg[dst[e]], 1);
}

#define SCAN_ELEMS 1024
__global__ void scan_block(const int* __restrict__ deg, int* __restrict__ row_ptr,
                           int* __restrict__ bsums) {
  __shared__ int s[256];
  int tid = threadIdx.x;
  int base = blockIdx.x * SCAN_ELEMS + tid * 4;
  int v0 = (base + 0 < NN) ? deg[base + 0] : 0;
  int v1 = (base + 1 < NN) ? deg[base + 1] : 0;
  int v2 = (base + 2 < NN) ? deg[base + 2] : 0;
  int v3 = (base + 3 < NN) ? deg[base + 3] : 0;
  int tot = v0 + v1 + v2 + v3;
  s[tid] = tot;
  __syncthreads();
  for (int d = 1; d < 256; d <<= 1) {
    int t = (tid >= d) ? s[tid - d] : 0;
    __syncthreads();
    s[tid] += t;
    __syncthreads();
  }
  int incl = s[tid];
  int ex = incl - tot;
  if (tid == 255) bsums[blockIdx.x] = incl;
  if (base + 0 < NN) row_ptr[base + 0] = ex;
  if (base + 1 < NN) row_ptr[base + 1] = ex + v0;
  if (base + 2 < NN) row_ptr[base + 2] = ex + v0 + v1;
  if (base + 3 < NN) row_ptr[base + 3] = ex + v0 + v1 + v2;
}

__global__ void scan_tops(int* __restrict__ bsums, int nb) {
  if (threadIdx.x == 0 && blockIdx.x == 0) {
    int acc = 0;
    for (int i = 0; i < nb; ++i) { int v = bsums[i]; bsums[i] = acc; acc += v; }
  }
}

__global__ void scan_add(int* __restrict__ row_ptr, const int* __restrict__ bsums,
                         int* __restrict__ cursor) {
  int i = blockIdx.x * 256 + threadIdx.x;
  if (i < NN) {
    int v = row_ptr[i] + bsums[i / SCAN_ELEMS];
    row_ptr[i] = v;
    cursor[i] = v;
  }
  if (i == 0) row_ptr[NN] = NE;
}

__global__ void scatter_kernel(const int* __restrict__ dst, int* __restrict__ cursor,
                               int* __restrict__ edge_idx) {
  int e = blockIdx.x * 256 + threadIdx.x;
  if (e < NE) {
    int pos = atomicAdd(&cursor[dst[e]], 1);
    edge_idx[pos] = e;
  }
}

// ---- per-node softmax + weighted aggregation: one wave per dst node
#define CHUNK 128
__global__ __launch_bounds__(256) void aggregate(
    const float* __restrict__ ft, const float* __restrict__ el,
    const float* __restrict__ er, const float* __restrict__ w,
    const int* __restrict__ src, const int* __restrict__ row_ptr,
    const int* __restrict__ edge_idx, const float* __restrict__ bias,
    float* __restrict__ out) {
  __shared__ float s_a[4][CHUNK];
  __shared__ int s_o[4][CHUNK];
  const int lane = threadIdx.x & 63;
  const int wv = threadIdx.x >> 6;
  const int n = blockIdx.x * 4 + wv;
  if (n >= NN) return;
  const int beg = row_ptr[n];
  const int deg = row_ptr[n + 1] - beg;
  const float ern = er[n];

  float me = -1e30f, mw = -1e30f;
  for (int i = lane; i < deg; i += 64) {
    int e = edge_idx[beg + i];
    float x = el[src[e]] + ern;
    x = (x > 0.f) ? x : NEG_SLOPE * x;
    me = fmaxf(me, x);
    mw = fmaxf(mw, w[e]);
  }
#pragma unroll
  for (int d = 1; d < 64; d <<= 1) {
    me = fmaxf(me, __shfl_xor(me, d));
    mw = fmaxf(mw, __shfl_xor(mw, d));
  }
  float se = 0.f, sw = 0.f;
  for (int i = lane; i < deg; i += 64) {
    int e = edge_idx[beg + i];
    float x = el[src[e]] + ern;
    x = (x > 0.f) ? x : NEG_SLOPE * x;
    se += __expf(x - me);
    sw += __expf(w[e] - mw);
  }
#pragma unroll
  for (int d = 1; d < 64; d <<= 1) {
    se += __shfl_xor(se, d);
    sw += __shfl_xor(sw, d);
  }
  const float ce = (1.f - ALPHA) / se;
  const float cw = ALPHA / sw;

  float2 acc = make_float2(0.f, 0.f);
  for (int cb = 0; cb < deg; cb += CHUNK) {
    int cnt = min(CHUNK, deg - cb);
    for (int i = lane; i < cnt; i += 64) {
      int e = edge_idx[beg + cb + i];
      float x = el[src[e]] + ern;
      x = (x > 0.f) ? x : NEG_SLOPE * x;
      s_a[wv][i] = __expf(x - me) * ce + __expf(w[e] - mw) * cw;
      s_o[wv][i] = src[e] * DOUT;
    }
    __builtin_amdgcn_wave_barrier();  // wave-synchronous LDS use (lockstep wave64)
    for (int i = 0; i < cnt; ++i) {
      float a = s_a[wv][i];
      const float2 v = *(const float2*)(ft + s_o[wv][i] + lane * 2);
      acc.x = fmaf(a, v.x, acc.x);
      acc.y = fmaf(a, v.y, acc.y);
    }
    __builtin_amdgcn_wave_barrier();
  }
  const float2 bb = *(const float2*)(bias + lane * 2);
  float2 o;
  o.x = acc.x + bb.x;
  o.y = acc.y + bb.y;
  *(float2*)(out + (size_t)n * DOUT + lane * 2) = o;
}

extern "C" void kernel_launch(void* const* d_in, const int* in_sizes, int n_in,
                              void* d_out, int out_size, void* d_ws, size_t ws_size,
                              hipStream_t stream) {
  const float* feat = (const float*)d_in[0];
  const float* w = (const float*)d_in[1];
  const float* fc_w = (const float*)d_in[2];
  const float* attn_l = (const float*)d_in[3];
  const float* attn_r = (const float*)d_in[4];
  const float* bias = (const float*)d_in[5];
  const int* src = (const int*)d_in[6];
  const int* dst = (const int*)d_in[7];
  float* out = (float*)d_out;

  char* ws = (char*)d_ws;
  size_t o = 0;
  auto take = [&](size_t bytes) {
    char* p = ws + o;
    o = (o + bytes + 255) & ~(size_t)255;
    return p;
  };
  float* ft = (float*)take((size_t)NN * DOUT * 4);
  float* el = (float*)take((size_t)NN * 4);
  float* er = (float*)take((size_t)NN * 4);
  unsigned short* b_hi = (unsigned short*)take((size_t)KIN * DOUT * 2);
  unsigned short* b_lo = (unsigned short*)take((size_t)KIN * DOUT * 2);
  int* deg = (int*)take((size_t)NN * 4);
  int* row_ptr = (int*)take((size_t)(NN + 1) * 4);
  int* cursor = (int*)take((size_t)NN * 4);
  int* bsums = (int*)take(64 * 4);
  int* edge_idx = (int*)take((size_t)NE * 4);

  hipMemsetAsync(deg, 0, (size_t)NN * 4, stream);
  prep_b<<<(KIN * DOUT + 255) / 256, 256, 0, stream>>>(fc_w, b_hi, b_lo);
  gemm_ft<<<(NN + 63) / 64, 256, 0, stream>>>(feat, b_hi, b_lo, attn_l, attn_r, ft, el, er);
  hist_kernel<<<(NE + 255) / 256, 256, 0, stream>>>(dst, deg);
  scan_block<<<(NN + SCAN_ELEMS - 1) / SCAN_ELEMS, 256, 0, stream>>>(deg, row_ptr, bsums);
  scan_tops<<<1, 64, 0, stream>>>(bsums, (NN + SCAN_ELEMS - 1) / SCAN_ELEMS);
  scan_add<<<(NN + 255) / 256, 256, 0, stream>>>(row_ptr, bsums, cursor);
  scatter_kernel<<<(NE + 255) / 256, 256, 0, stream>>>(dst, cursor, edge_idx);
  aggregate<<<(NN + 3) / 4, 256, 0, stream>>>(ft, el, er, w, src, row_ptr, edge_idx, bias, out);
}